// Round 4
// baseline (270.586 us; speedup 1.0000x reference)
//
#include <hip/hip_runtime.h>

#define NRELS 64
#define BLOCK 256
#define EPT   8     // edges per thread; 2048 edges per block

// ln(x) via v_log_f32 (log2, ~1 ulp) * ln2. Values here are >= ~5e-3.
// Output threshold 0.675 abs on values up to ~454 -> ~1.5e-3 relative
// budget; these approximations are ~1e-7.
__device__ __forceinline__ float fast_ln(float x) {
    return 0.69314718056f * __builtin_amdgcn_logf(x);
}
__device__ __forceinline__ float fast_rcp(float x) {
    return __builtin_amdgcn_rcpf(x);
}
__device__ __forceinline__ float fast_rsq(float x) {
    return __builtin_amdgcn_rsqf(x);
}

// Faithful sparsemax for d=3 (Martins & Astudillo 2016).
__device__ __forceinline__ void sparsemax3(float z0, float z1, float z2,
                                           float& o0, float& o1, float& o2) {
    float lo01 = fminf(z0, z1), hi01 = fmaxf(z0, z1);
    float s2 = fminf(lo01, z2);          // min of all
    float mx = fmaxf(lo01, z2);
    float s0 = fmaxf(hi01, mx);          // max of all
    float s1 = fminf(hi01, mx);          // middle
    float cs2 = s0 + s1;
    float cs3 = cs2 + s2;
    bool k2 = (1.0f + 2.0f * s1 > cs2);
    bool k3 = (1.0f + 3.0f * s2 > cs3);
    int k = 1 + (int)k2 + (int)k3;
    float csk = (k == 1) ? s0 : ((k == 2) ? cs2 : cs3);
    float rk  = (k == 1) ? 1.0f : ((k == 2) ? 0.5f : 0.33333334f);
    float tau = (csk - 1.0f) * rk;
    o0 = fmaxf(z0 - tau, 0.0f);
    o1 = fmaxf(z1 - tau, 0.0f);
    o2 = fmaxf(z2 - tau, 0.0f);
}

__device__ __forceinline__ void edge_compute(
    float p0, float p1, float p2,
    float q0, float q1, float q2,
    int r, const float* sM, const float* sB,
    float zeps, float sf,
    float& a0o, float& a1o, float& a2o) {
    // M row-major 3x3 padded to 12 floats/rel: 2x ds_read_b128 + 1x b32.
    const float4 ma = *(const float4*)&sM[r * 12];       // m00 m01 m02 m10
    const float4 mb = *(const float4*)&sM[r * 12 + 4];   // m11 m12 m20 m21
    const float  m22 = sM[r * 12 + 8];
    float c0 = ma.x * q0 + ma.y * q1 + ma.z * q2;
    float c1 = ma.w * q0 + mb.x * q1 + mb.y * q2;
    float c2 = mb.z * q0 + mb.w * q1 + m22 * q2;
    sparsemax3(c0, c1, c2, c0, c1, c2);
    sparsemax3(c0, c1, c2, c0, c1, c2);   // reference applies it twice
    sparsemax3(p0, p1, p2, p0, p1, p2);
    const float4 bv = *(const float4*)&sB[r * 4];        // b0 b1 b2 pad
    float a0 = (1.0f - bv.x) * p0 + bv.x * c0;
    float a1 = (1.0f - bv.y) * p1 + bv.y * c1;
    float a2 = (1.0f - bv.z) * p2 + bv.z * c2;
    float z0 = fmaxf(p0 + c0, zeps);
    float z1 = fmaxf(p1 + c1, zeps);
    float z2 = fmaxf(p2 + c2, zeps);
    float rs = fast_rcp(z0 + z1 + z2);
    z0 *= rs; z1 *= rs; z2 *= rs;
    float ent = -(z0 * fast_ln(z0) + z1 * fast_ln(z1) + z2 * fast_ln(z2));
    float dot = p0 * c0 + p1 * c1 + p2 * c2;
    float pp = p0 * p0 + p1 * p1 + p2 * p2;
    float cc = c0 * c0 + c1 * c1 + c2 * c2;
    float cosv = 0.1f + dot * fast_rsq(fmaxf(pp * cc, 1e-20f));
    float scale = sf * cosv * fast_rcp(ent);
    a0o = fmaxf(a0 * scale, 0.001f);
    a1o = fmaxf(a1 * scale, 0.001f);
    a2o = fmaxf(a2 * scale, 0.001f);
}

__global__ __launch_bounds__(BLOCK, 2) void alpha_kernel(
    const float* __restrict__ prnt, const float* __restrict__ child,
    const float* __restrict__ Mg, const float* __restrict__ betag,
    const float* __restrict__ zeps_p, const float* __restrict__ sf_p,
    const int* __restrict__ rels, float* __restrict__ out, int n_edges) {
    __shared__ __align__(16) float sM[NRELS * 12];
    __shared__ __align__(16) float sB[NRELS * 4];
    for (int i = threadIdx.x; i < NRELS * 9; i += BLOCK) {
        int r = i / 9, rem = i - r * 9;
        sM[r * 12 + rem] = Mg[i];
    }
    for (int i = threadIdx.x; i < NRELS * 3; i += BLOCK) {
        int r = i / 3, rem = i - r * 3;
        sB[r * 4 + rem] = betag[i];
    }
    __syncthreads();

    const float zeps = zeps_p[0];
    const float sf   = sf_p[0];
    const long tg = (long)blockIdx.x * BLOCK + threadIdx.x;  // thread group id
    const long e0 = tg * EPT;

    if (e0 + EPT <= n_edges) {
        // ---- issue ALL 14 global loads back-to-back: 8 edges = 24 floats
        //      = 6 float4 from each of prnt/child + 2 int4 of rels.
        //      ~56 payload VGPRs in flight -> 8x the per-wave MLP of R1-R3.
        const float4* p4 = (const float4*)prnt;
        const float4* c4 = (const float4*)child;
        float4 P4[6], C4[6];
        #pragma unroll
        for (int k = 0; k < 6; k++) P4[k] = p4[6 * tg + k];
        #pragma unroll
        for (int k = 0; k < 6; k++) C4[k] = c4[6 * tg + k];
        int4 ra = ((const int4*)rels)[2 * tg];
        int4 rb = ((const int4*)rels)[2 * tg + 1];

        const float* P = (const float*)P4;
        const float* C = (const float*)C4;
        int R[8] = {ra.x, ra.y, ra.z, ra.w, rb.x, rb.y, rb.z, rb.w};
        float O[24];
        #pragma unroll
        for (int e = 0; e < EPT; e++) {
            edge_compute(P[3 * e], P[3 * e + 1], P[3 * e + 2],
                         C[3 * e], C[3 * e + 1], C[3 * e + 2],
                         R[e], sM, sB, zeps, sf,
                         O[3 * e], O[3 * e + 1], O[3 * e + 2]);
        }

        float4* o4 = (float4*)out;
        const float4* O4 = (const float4*)O;
        #pragma unroll
        for (int k = 0; k < 6; k++) o4[6 * tg + k] = O4[k];
    } else if (e0 < n_edges) {
        // ---- tail: < EPT edges for this thread, scalar (defensive)
        for (long e = e0; e < n_edges; e++) {
            float a0, a1, a2;
            edge_compute(prnt[3 * e], prnt[3 * e + 1], prnt[3 * e + 2],
                         child[3 * e], child[3 * e + 1], child[3 * e + 2],
                         rels[e], sM, sB, zeps, sf, a0, a1, a2);
            out[3 * e] = a0; out[3 * e + 1] = a1; out[3 * e + 2] = a2;
        }
    }
}

extern "C" void kernel_launch(void* const* d_in, const int* in_sizes, int n_in,
                              void* d_out, int out_size, void* d_ws, size_t ws_size,
                              hipStream_t stream) {
    const float* prnt  = (const float*)d_in[0];
    const float* child = (const float*)d_in[1];
    const float* Mg    = (const float*)d_in[2];
    const float* betag = (const float*)d_in[3];
    const float* zeps  = (const float*)d_in[4];
    const float* sf    = (const float*)d_in[5];
    const int*   rels  = (const int*)d_in[6];
    float* out = (float*)d_out;

    int n_edges = in_sizes[0] / 3;
    long nthreads = ((long)n_edges + EPT - 1) / EPT;
    int nblocks = (int)((nthreads + BLOCK - 1) / BLOCK);
    alpha_kernel<<<nblocks, BLOCK, 0, stream>>>(
        prnt, child, Mg, betag, zeps, sf, rels, out, n_edges);
}